// Round 7
// baseline (268.743 us; speedup 1.0000x reference)
//
#include <hip/hip_runtime.h>

typedef unsigned long long u64;
typedef unsigned int u32;
typedef float f4n __attribute__((ext_vector_type(4)));   // native vec4 for NT stores

static constexpr int NF = 17;      // features per point
static constexpr int BCOL = 9;     // beta column
static constexpr int CCOL = 14;    // first ccoord column (17-3)
static constexpr int RPB = 512;    // rows per block in filter part
static constexpr int CHUNK = 3072; // LDS NMS chunk capacity (75 KB LDS total)
static constexpr int REFCAP = 64;  // 0.7-separated points in unit cube <= 27, so 64 is safe
static constexpr int GB = 8;       // load-batch depth in k_rest sweeps

#define T_B_F ((float)0.2)         // matches numpy float32(0.2)
#define R2_F  ((float)(0.7*0.7))   // matches numpy promotion

__device__ __forceinline__ u64 shfl_down_u64(u64 v, int off){
    u32 lo = (u32)v, hi = (u32)(v >> 32);
    lo = __shfl_down(lo, off, 64);
    hi = __shfl_down(hi, off, 64);
    return ((u64)hi << 32) | lo;
}

// distance with NO fp contraction — must match numpy (mul,mul,mul,add,add)
__device__ __forceinline__ float dist2(float cx, float cy, float cz,
                                       float rx, float ry, float rz){
    #pragma clang fp contract(off)
    float dx = cx - rx, dy = cy - ry, dz = cz - rz;
    float sx = dx * dx, sy = dy * dy, sz = dz * dz;
    return (sx + sy) + sz;
}

__device__ __forceinline__ u64 makeKey(float beta, u32 idx){
    return ((u64)__float_as_uint(beta) << 32) | (u64)(0xFFFFFFFFu - idx);
}

// monotone bucket over beta in [0.2, 1.0) -> [0,255]
__device__ __forceinline__ int bucketOf(float b){
    int v = (int)((b - 0.2f) * 320.0f);
    return v > 255 ? 255 : v;
}

// block-wide argmax with slot payload; blockDim = 1024 (16 waves)
__device__ __forceinline__ void blockArgmax(u64 bk, int bs,
                                            u64* wkey, int* wslot,
                                            u64* skey, int* sslot){
    int tid = threadIdx.x, lid = tid & 63, wid = tid >> 6;
    #pragma unroll
    for (int off = 32; off > 0; off >>= 1){
        u64 ok = shfl_down_u64(bk, off);
        int os = __shfl_down(bs, off, 64);
        if (ok > bk){ bk = ok; bs = os; }
    }
    if (lid == 0){ wkey[wid] = bk; wslot[wid] = bs; }
    __syncthreads();
    if (wid == 0){
        u64 k2 = (lid < 16) ? wkey[lid] : 0;
        int s2 = (lid < 16) ? wslot[lid] : -1;
        #pragma unroll
        for (int off = 8; off > 0; off >>= 1){
            u64 ok = shfl_down_u64(k2, off);
            int os = __shfl_down(s2, off, 64);
            if (ok > k2){ k2 = ok; s2 = os; }
        }
        if (lid == 0){ *skey = k2; *sslot = s2; }
    }
    __syncthreads();
}

// LDS NMS: fused suppress+argmax pass, 2 barriers/round. refs appended to LDS.
__device__ int lds_nms_fast(float4* cp, float* cb, int* ci, int m,
                            u64* wkey, int* wslot, u64* skey, int* sslot,
                            float4* lref, int* lrefi, int nref)
{
    int tid = threadIdx.x;
    u64 bk = 0; int bs = -1;
    for (int k = tid; k < m; k += 1024){
        u64 kk = makeKey(cb[k], (u32)ci[k]);
        if (kk > bk){ bk = kk; bs = k; }
    }
    blockArgmax(bk, bs, wkey, wslot, skey, sslot);
    while (*skey != 0){
        int rs = *sslot;
        float4 rv = cp[rs];
        if (tid == 0 && nref < REFCAP){ lref[nref] = rv; lrefi[nref] = ci[rs]; }
        nref++;
        bk = 0; bs = -1;
        for (int k = tid; k < m; k += 1024){
            float b = cb[k];
            if (b >= 0.f){
                float4 p = cp[k];
                if (dist2(p.x, p.y, p.z, rv.x, rv.y, rv.z) <= R2_F) cb[k] = -1.f;
                else { u64 kk = makeKey(b, (u32)ci[k]); if (kk > bk){ bk = kk; bs = k; } }
            }
        }
        blockArgmax(bk, bs, wkey, wslot, skey, sslot);
    }
    return nref;
}

// ---------------- kernel 1: fused NT-zero of out + filter/histogram ----------
// blockIdx % 3 == 2 -> zero part (interleaved so write stream overlaps reads)
__global__ __launch_bounds__(256) void k_main(
    const float4* __restrict__ x4, f4n* __restrict__ out4, int n4out,
    int* __restrict__ cnt, int* __restrict__ hist,
    float4* __restrict__ cand_xyz, int* __restrict__ cand_idx,
    int P, int chunksPerEvent)
{
    __shared__ float4 lrow[RPB];              // (cx,cy,cz,beta) per row — 8 KB
    __shared__ int lh[256];
    __shared__ int swc[4], swb[4], sbase;

    int b = blockIdx.x;
    int mod = b % 3;
    if (mod == 2){                            // -------- zero part --------
        int zi = b / 3;
        int zBlocks = gridDim.x / 3;
        int i = zi * 256 + threadIdx.x;
        int stride = zBlocks * 256;
        f4n z = {0.f, 0.f, 0.f, 0.f};
        for (; i < n4out; i += stride) __builtin_nontemporal_store(z, &out4[i]);
        return;
    }
    // -------- filter part --------
    int fi = (b / 3) * 2 + mod;
    int e = fi / chunksPerEvent;
    int chunk = fi % chunksPerEvent;
    int rowStart = chunk * RPB;
    size_t tile4 = (size_t)fi * (RPB * NF / 4);
    int tid = threadIdx.x;
    lh[tid] = 0;

    const int N4 = RPB * NF / 4;
    for (int i = tid; i < N4; i += 256){
        float4 v = x4[tile4 + i];
        float vv[4] = {v.x, v.y, v.z, v.w};
        int f0 = 4 * i;
        #pragma unroll
        for (int j = 0; j < 4; j++){
            int flat = f0 + j;
            int row = flat / NF;
            int col = flat - row * NF;
            if (col == BCOL)       ((float*)&lrow[row])[3] = vv[j];
            else if (col >= CCOL)  ((float*)&lrow[row])[col - CCOL] = vv[j];
        }
    }
    __syncthreads();

    int lid = tid & 63, wid = tid >> 6;
    float4 a0 = lrow[tid], a1 = lrow[tid + 256];
    bool k0 = (a0.w >= T_B_F), k1 = (a1.w >= T_B_F);
    u64 bal0 = __ballot(k0), bal1 = __ballot(k1);
    int wcnt = __popcll(bal0) + __popcll(bal1);
    if (k0) atomicAdd(&lh[bucketOf(a0.w)], 1);
    if (k1) atomicAdd(&lh[bucketOf(a1.w)], 1);
    if (lid == 0) swc[wid] = wcnt;
    __syncthreads();
    if (tid == 0){
        int tot = 0;
        for (int w = 0; w < 4; w++){ swb[w] = tot; tot += swc[w]; }
        sbase = tot ? atomicAdd(&cnt[e], tot) : 0;
    }
    __syncthreads();
    int base = sbase + swb[wid];
    u64 lm = (1ull << lid) - 1;
    size_t eoff = (size_t)e * P;
    if (k0){
        int pos = base + __popcll(bal0 & lm);
        cand_xyz[eoff + pos] = a0;
        cand_idx[eoff + pos] = rowStart + tid;
    }
    if (k1){
        int pos = base + __popcll(bal0) + __popcll(bal1 & lm);
        cand_xyz[eoff + pos] = a1;
        cand_idx[eoff + pos] = rowStart + tid + 256;
    }
    if (lh[tid]) atomicAdd(&hist[e * 256 + tid], lh[tid]);
}

// ---------------- kernel 2: whole tail, one block per event ------------------
// cutoff -> batched gather top chunk -> LDS NMS -> batched suppress sweep
// (survivors to LDS) -> LDS NMS survivors -> scatter rows -> splits.
__global__ __launch_bounds__(1024) void k_rest(
    const float* __restrict__ x, float* __restrict__ out,
    float4* __restrict__ cand_xyz, int* __restrict__ cand_idx,   // also spill buf
    const int* __restrict__ cnt, const int* __restrict__ hist,
    float4* __restrict__ sB_xyz, int* __restrict__ sB_idx,       // fallback pong
    int* __restrict__ ncond, int* __restrict__ done, int P, int E)
{
    __shared__ float4 cp[CHUNK];   // 48 KB
    __shared__ float cb[CHUNK];    // 12 KB
    __shared__ int ci[CHUNK];      // 12 KB
    __shared__ int lh[256];
    __shared__ float4 lref[REFCAP];
    __shared__ int lrefi[REFCAP];
    __shared__ u64 wkey[16]; __shared__ int wslot[16];
    __shared__ u64 skey; __shared__ int sslot;
    __shared__ int sm, scut, sLast;

    int e = blockIdx.x, tid = threadIdx.x, lid = tid & 63, wid = tid >> 6;
    size_t eoff = (size_t)e * P;
    int n = cnt[e];

    if (tid < 256) lh[tid] = hist[e * 256 + tid];
    if (tid == 0) sm = 0;
    __syncthreads();
    if (tid == 0){
        int tot = 0, cu = 0;
        for (int b = 255; b >= 0; b--){
            if (tot + lh[b] > CHUNK){ cu = b + 1; break; }
            tot += lh[b];
        }
        scut = cu;
    }
    __syncthreads();
    int cut = scut;
    u64 lm = (1ull << lid) - 1;

    // ---- phase A: batched gather of top-cutoff candidates into LDS ----
    for (int i0 = 0; i0 < n; i0 += 1024 * GB){
        float4 v[GB]; int id[GB]; bool sel[GB]; u64 bal[GB];
        #pragma unroll
        for (int k = 0; k < GB; k++){
            int i = i0 + k * 1024 + tid;
            bool inb = i < n;
            int ii = inb ? i : 0;
            v[k] = cand_xyz[eoff + ii];
            id[k] = cand_idx[eoff + ii];
            sel[k] = inb && (bucketOf(v[k].w) >= cut);
            bal[k] = __ballot(sel[k]);
        }
        int wcnt = 0;
        #pragma unroll
        for (int k = 0; k < GB; k++) wcnt += __popcll(bal[k]);
        int b_ = 0;
        if (lid == 0) b_ = wcnt ? atomicAdd(&sm, wcnt) : 0;
        b_ = __shfl(b_, 0, 64);
        #pragma unroll
        for (int k = 0; k < GB; k++){
            if (sel[k]){
                int p = b_ + __popcll(bal[k] & lm);
                cp[p] = v[k]; cb[p] = v[k].w; ci[p] = id[k];
            }
            b_ += __popcll(bal[k]);
        }
    }
    __syncthreads();
    int m = sm;                          // <= CHUNK by cutoff construction

    // ---- phase B: LDS NMS of top chunk ----
    int nref = lds_nms_fast(cp, cb, ci, m, wkey, wslot, &skey, &sslot,
                            lref, lrefi, 0);
    if (nref > REFCAP) nref = REFCAP;    // mathematically unreachable
    if (tid == 0) sm = 0;
    __syncthreads();

    // ---- phase C: batched suppress sweep; survivors into LDS (spill->cand) ----
    for (int i0 = 0; i0 < n; i0 += 1024 * GB){
        float4 v[GB]; int id[GB]; bool kp[GB]; u64 bal[GB];
        #pragma unroll
        for (int k = 0; k < GB; k++){
            int i = i0 + k * 1024 + tid;
            bool inb = i < n;
            int ii = inb ? i : 0;
            v[k] = cand_xyz[eoff + ii];
            id[k] = cand_idx[eoff + ii];
            kp[k] = inb && (bucketOf(v[k].w) < cut);
        }
        #pragma unroll
        for (int k = 0; k < GB; k++){
            if (kp[k]){
                for (int r = 0; r < nref; r++){
                    float4 rf = lref[r];
                    if (dist2(v[k].x, v[k].y, v[k].z, rf.x, rf.y, rf.z) <= R2_F){
                        kp[k] = false; break;
                    }
                }
            }
            bal[k] = __ballot(kp[k]);
        }
        int wcnt = 0;
        #pragma unroll
        for (int k = 0; k < GB; k++) wcnt += __popcll(bal[k]);
        int b_ = 0;
        if (lid == 0) b_ = wcnt ? atomicAdd(&sm, wcnt) : 0;
        b_ = __shfl(b_, 0, 64);
        #pragma unroll
        for (int k = 0; k < GB; k++){
            if (kp[k]){
                int p = b_ + __popcll(bal[k] & lm);
                if (p < CHUNK){ cp[p] = v[k]; cb[p] = v[k].w; ci[p] = id[k]; }
                else { cand_xyz[eoff + p] = v[k]; cand_idx[eoff + p] = id[k]; }  // spill
            }
            b_ += __popcll(bal[k]);
        }
    }
    __syncthreads();
    int m2 = sm;

    // ---- fallback (unreached for bench data): shrink survivors > CHUNK ----
    if (m2 > CHUNK){
        for (int i = tid; i < CHUNK; i += 1024){
            cand_xyz[eoff + i] = make_float4(cp[i].x, cp[i].y, cp[i].z, cb[i]);
            cand_idx[eoff + i] = ci[i];
        }
        __syncthreads();
        const float4* sx = cand_xyz + eoff; const int* si = cand_idx + eoff;
        float4* dx = sB_xyz + eoff; int* di = sB_idx + eoff;
        while (m2 > CHUNK){
            u64 bk = 0; int bs = -1;
            for (int i = tid; i < m2; i += 1024){
                u64 kk = makeKey(sx[i].w, (u32)si[i]);
                if (kk > bk){ bk = kk; bs = i; }
            }
            blockArgmax(bk, bs, wkey, wslot, &skey, &sslot);
            float4 rv = sx[sslot];
            if (tid == 0 && nref < REFCAP){ lref[nref] = rv; lrefi[nref] = si[sslot]; }
            nref++;
            if (tid == 0) sm = 0;
            __syncthreads();
            for (int i0 = 0; i0 < m2; i0 += 1024){
                int i = i0 + tid;
                bool keep = false; float4 v = make_float4(0.f,0.f,0.f,0.f); int id_ = 0;
                if (i < m2){
                    v = sx[i]; id_ = si[i];
                    keep = !(dist2(v.x, v.y, v.z, rv.x, rv.y, rv.z) <= R2_F);
                }
                u64 bal = __ballot(keep);
                int cw = __popcll(bal);
                int b_ = 0;
                if (lid == 0) b_ = cw ? atomicAdd(&sm, cw) : 0;
                b_ = __shfl(b_, 0, 64);
                if (keep){
                    int p_ = b_ + __popcll(bal & lm);
                    dx[p_] = v; di[p_] = id_;
                }
            }
            __syncthreads();
            m2 = sm;
            { const float4* t = sx; sx = dx; dx = (float4*)t; }
            { const int* t = si; si = di; di = (int*)t; }
            __syncthreads();
        }
        for (int i = tid; i < m2; i += 1024){
            float4 v = sx[i];
            cp[i] = v; cb[i] = v.w; ci[i] = si[i];
        }
        __syncthreads();
    }

    // ---- phase D: LDS NMS of survivors (greedy continues exactly) ----
    nref = lds_nms_fast(cp, cb, ci, m2, wkey, wslot, &skey, &sslot,
                        lref, lrefi, nref);
    if (nref > REFCAP) nref = REFCAP;

    // ---- phase E: scatter condensate rows (out zeroed by k_main) ----
    for (int i = tid; i < nref * NF; i += 1024){
        int j = i / NF, f = i - j * NF;
        int row = lrefi[j];
        size_t b = ((size_t)e * P + row) * NF;
        out[b + f] = x[b + f];
    }
    if (tid == 0) atomicExch(&ncond[e], nref);
    __threadfence();
    __syncthreads();
    if (tid == 0) sLast = atomicAdd(done, 1);
    __syncthreads();
    if (sLast == E - 1 && tid == 0){
        size_t so = (size_t)E * P * NF;
        int s = 0;
        out[so] = 0.f;
        for (int i = 0; i < E; i++){
            s += atomicAdd(&ncond[i], 0);
            out[so + i + 1] = (float)s;
        }
    }
}

extern "C" void kernel_launch(void* const* d_in, const int* in_sizes, int n_in,
                              void* d_out, int out_size, void* d_ws, size_t ws_size,
                              hipStream_t stream) {
    const float* x = (const float*)d_in[0];
    int N = in_sizes[0] / NF;
    int E = in_sizes[1] - 1;
    int P = N / E;
    float* out = (float*)d_out;
    char* ws = (char*)d_ws;

    // ws layout
    int* cnt   = (int*)(ws + 0);        // [E]
    int* ncond = (int*)(ws + 64);       // [E]
    int* done  = (int*)(ws + 128);      // [1]
    int* hist  = (int*)(ws + 1024);     // [E][256] = 16 KB -> ends at 17408
    size_t o = 32768;
    float4* cand_xyz = (float4*)(ws + o);                    // E*P*16 = 16 MB (+spill)
    int* cand_idx    = (int*)(ws + o + (size_t)E*P*16);      // 4 MB
    float4* sB_xyz   = (float4*)(ws + o + (size_t)E*P*20);   // 16 MB (fallback pong)
    int* sB_idx      = (int*)(ws + o + (size_t)E*P*36);      // 4 MB

    hipMemsetAsync(ws, 0, 17408, stream);    // cnt, ncond, done, hist

    int chunksPerEvent = P / RPB;            // 128
    int filterBlocks = E * chunksPerEvent;   // 2048
    int zeroBlocks = filterBlocks / 2;       // 1024 (grid = 3*zeroBlocks)
    int n4out = (N * NF) / 4;
    k_main<<<filterBlocks + zeroBlocks, 256, 0, stream>>>(
        (const float4*)x, (f4n*)out, n4out, cnt, hist, cand_xyz, cand_idx,
        P, chunksPerEvent);

    k_rest<<<E, 1024, 0, stream>>>(
        x, out, cand_xyz, cand_idx, cnt, hist, sB_xyz, sB_idx,
        ncond, done, P, E);
}